// Round 7
// baseline (1324.018 us; speedup 1.0000x reference)
//
#include <hip/hip_runtime.h>

// LIF spiking net forward, v6 — exact fixed-point i8 MFMA GEMM, 2 blocks/CU.
//   W -> 4 signed base-256 digits of round(W * 2^34)  (exact, top digit <=85)
//   S (binary fp32) -> i8
//   I = sum_d 2^(8d) * (S_i8 @ digit_d^T)  combined in int64, one fp32 round.
// v6: LDS 64 KB (pitch 64 + XOR swizzle, both sides) -> 2 blocks/CU;
//     launch_bounds(512,4); phase-unrolled prefetching LIF scan.

#define N_IN   1024
#define N_OUT  512
#define DECAY_F 0.95122942450071400910f
#define SCALE     17179869184.0            // 2^34
#define SCALE_INV 5.8207660913467407e-11f  // 2^-34

typedef int  v4i  __attribute__((ext_vector_type(4)));
typedef int  v16i __attribute__((ext_vector_type(16)));

// ---------------- kernel 1: S fp32 -> i8 ----------------
__global__ __launch_bounds__(256) void s_to_i8(const float* __restrict__ S,
                                               signed char* __restrict__ S8,
                                               int n16) {
    const int g = blockIdx.x * 256 + threadIdx.x;
    if (g >= n16) return;
    const float4* p = reinterpret_cast<const float4*>(S) + (size_t)g * 4;
    union { signed char c[16]; int4 v; } u;
#pragma unroll
    for (int q = 0; q < 4; ++q) {
        const float4 v = p[q];
        u.c[q * 4 + 0] = (signed char)(v.x != 0.f);
        u.c[q * 4 + 1] = (signed char)(v.y != 0.f);
        u.c[q * 4 + 2] = (signed char)(v.z != 0.f);
        u.c[q * 4 + 3] = (signed char)(v.w != 0.f);
    }
    reinterpret_cast<int4*>(S8)[g] = u.v;
}

// ---------------- kernel 2: W -> 4 digit planes ----------------
__global__ __launch_bounds__(256) void w_digits(const float* __restrict__ W,
                                                signed char* __restrict__ D8) {
    const int n  = blockIdx.x;            // 0..511
    const int k0 = threadIdx.x * 4;       // 0..1020
    const float4 wv = *reinterpret_cast<const float4*>(W + (size_t)n * N_IN + k0);
    const float ww[4] = {wv.x, wv.y, wv.z, wv.w};
    int pk[4] = {0, 0, 0, 0};
#pragma unroll
    for (int j = 0; j < 4; ++j) {
        long long wi = (long long)rint((double)ww[j] * SCALE);
        const int d0 = (int)((wi + 128) & 255) - 128; wi = (wi - d0) >> 8;
        const int d1 = (int)((wi + 128) & 255) - 128; wi = (wi - d1) >> 8;
        const int d2 = (int)((wi + 128) & 255) - 128; wi = (wi - d2) >> 8;
        const int d3 = (int)wi;           // |d3| <= 85
        pk[0] |= (d0 & 255) << (8 * j);
        pk[1] |= (d1 & 255) << (8 * j);
        pk[2] |= (d2 & 255) << (8 * j);
        pk[3] |= (d3 & 255) << (8 * j);
    }
#pragma unroll
    for (int d = 0; d < 4; ++d)
        *reinterpret_cast<int*>(D8 + (size_t)(d * N_OUT + n) * N_IN + k0) = pk[d];
}

// ---------------- kernel 3: i8 MFMA GEMM, depth-2 pipeline ----------------
#define BM 256
#define BN 64
#define BK 64
#define PITCH 64
#define SWZ(row, col) ((col) ^ (((row) & 3) << 4))
#define ABUF (BM * PITCH)
#define ASH(buf) (lds + (buf) * ABUF)
#define BSH(buf) (lds + 2 * ABUF + (buf) * ABUF)

__global__ __launch_bounds__(512, 4) void gemm_i8(
        const signed char* __restrict__ S8,   // (M, 1024)
        const signed char* __restrict__ D8,   // (2048, 1024), row = d*512+n
        float* __restrict__ I, int M) {       // (M, 512)
    extern __shared__ signed char lds[];

    const int tid  = threadIdx.x;
    const int lane = tid & 63;
    const int w    = tid >> 6;
    const int wwm  = w >> 1;            // 0..3 -> M offset *64
    const int wwn  = w & 1;             // 0..1 -> N offset *32

    // XCD-aware swizzle: contiguous bm-range per XCD for A-tile L2 reuse.
    const int nx  = M / BM;                       // 125
    const int u   = (blockIdx.x & 7) * nx + (blockIdx.x >> 3);
    const int bm  = u >> 3;
    const int bn  = u & 7;
    const int m0 = bm * BM;
    const int n0 = bn * BN;

    const int srow = tid >> 2;           // 0..127
    const int scol = (tid & 3) * 16;     // 0..48
    const int swcol = SWZ(srow, scol);   // swizzled write column

    v16i acc[2][4];
#pragma unroll
    for (int mf = 0; mf < 2; ++mf)
#pragma unroll
        for (int d = 0; d < 4; ++d)
#pragma unroll
            for (int i = 0; i < 16; ++i) acc[mf][d][i] = 0;

    // two named register staging sets (compile-time indexed; rule #20)
    int4 pa0, pa1, pb0, pb1;
    int4 qa0, qa1, qb0, qb1;

#define LOADT(SET, kt)                                                            \
    SET##a0 = *reinterpret_cast<const int4*>(S8 + (size_t)(m0 + srow) * N_IN + (kt) * BK + scol);        \
    SET##a1 = *reinterpret_cast<const int4*>(S8 + (size_t)(m0 + srow + 128) * N_IN + (kt) * BK + scol);  \
    SET##b0 = *reinterpret_cast<const int4*>(D8 + (size_t)(((srow >> 6) * N_OUT) + n0 + (srow & 63)) * N_IN + (kt) * BK + scol);            \
    SET##b1 = *reinterpret_cast<const int4*>(D8 + (size_t)(((srow >> 6) * N_OUT + 2 * N_OUT) + n0 + (srow & 63)) * N_IN + (kt) * BK + scol);

#define WRITET(buf, SET)                                                          \
    *reinterpret_cast<int4*>(ASH(buf) + (srow) * PITCH + swcol) = SET##a0;        \
    *reinterpret_cast<int4*>(ASH(buf) + (srow + 128) * PITCH + SWZ(srow + 128, scol)) = SET##a1;   \
    *reinterpret_cast<int4*>(BSH(buf) + (srow) * PITCH + swcol) = SET##b0;        \
    *reinterpret_cast<int4*>(BSH(buf) + (srow + 128) * PITCH + SWZ(srow + 128, scol)) = SET##b1;

    const int fr = lane & 31;                 // fragment row/col
    const int kh = (lane >> 5) * 16;          // k-half byte offset

#define COMPUTE(buf)                                                              \
    _Pragma("unroll")                                                             \
    for (int ksub = 0; ksub < 2; ++ksub) {                                        \
        const int kb = ksub * 32 + kh;                                            \
        const int ra0_ = wwm * 64 + fr;                                           \
        const int ra1_ = wwm * 64 + 32 + fr;                                      \
        v4i af0 = *reinterpret_cast<const v4i*>(ASH(buf) + ra0_ * PITCH + SWZ(ra0_, kb));       \
        v4i af1 = *reinterpret_cast<const v4i*>(ASH(buf) + ra1_ * PITCH + SWZ(ra1_, kb));       \
        v4i bf[4];                                                                \
        _Pragma("unroll")                                                         \
        for (int d = 0; d < 4; ++d) {                                             \
            const int rb__ = d * 64 + wwn * 32 + fr;                              \
            bf[d] = *reinterpret_cast<const v4i*>(BSH(buf) + rb__ * PITCH + SWZ(rb__, kb)); \
        }                                                                         \
        __builtin_amdgcn_s_setprio(1);                                            \
        _Pragma("unroll")                                                         \
        for (int d = 0; d < 4; ++d) {                                             \
            acc[0][d] = __builtin_amdgcn_mfma_i32_32x32x32_i8(af0, bf[d], acc[0][d], 0, 0, 0); \
            acc[1][d] = __builtin_amdgcn_mfma_i32_32x32x32_i8(af1, bf[d], acc[1][d], 0, 0, 0); \
        }                                                                         \
        __builtin_amdgcn_s_setprio(0);                                            \
    }

    // prologue: tile0 -> LDS buf0; tile1 -> p; tile2 -> q (in flight)
    LOADT(p, 0);
    WRITET(0, p);
    LOADT(p, 1);
    LOADT(q, 2);
    __syncthreads();

#pragma unroll 1
    for (int kt = 0; kt < 16; kt += 2) {
        WRITET(1, p);
        if (kt + 3 <= 15) { LOADT(p, kt + 3); }
        COMPUTE(0);
        __syncthreads();
        if (kt + 2 <= 15) {
            WRITET(0, q);
            if (kt + 4 <= 15) { LOADT(q, kt + 4); }
        }
        COMPUTE(1);
        __syncthreads();
    }

    // epilogue: combine digits in int64, one fp32 rounding
    const int col = fr;
    const int rb_ = (lane >> 5) * 4;
#pragma unroll
    for (int mf = 0; mf < 2; ++mf) {
#pragma unroll
        for (int reg = 0; reg < 16; ++reg) {
            const int row = (reg & 3) + 8 * (reg >> 2) + rb_;
            const long long v =
                ((long long)acc[mf][3][reg] << 24) + ((long long)acc[mf][2][reg] << 16) +
                ((long long)acc[mf][1][reg] << 8) + (long long)acc[mf][0][reg];
            I[(size_t)(m0 + wwm * 64 + mf * 32 + row) * N_OUT + n0 + wwn * 32 + col] =
                (float)v * SCALE_INV;
        }
    }
}
#undef LOADT
#undef WRITET
#undef COMPUTE

// ---------------- kernel 4: LIF scan, phase-unrolled prefetch ----------------
#define UT 50
__global__ __launch_bounds__(64) void lif_scan3(float* __restrict__ IO, int T) {
    const int idx = blockIdx.x * 64 + threadIdx.x;   // chain id, 16384 total
    const int b = idx >> 9, o = idx & (N_OUT - 1);
    float* p = IO + (size_t)b * T * N_OUT + o;
    float ca[UT], cb[UT];
    float v = 0.f;
#pragma unroll
    for (int j = 0; j < UT; ++j) ca[j] = p[(size_t)j * N_OUT];
#pragma unroll 1
    for (int t0 = 0; t0 < T; t0 += 2 * UT) {
        if (t0 + UT < T) {
#pragma unroll
            for (int j = 0; j < UT; ++j) cb[j] = p[(size_t)(t0 + UT + j) * N_OUT];
        }
#pragma unroll
        for (int j = 0; j < UT; ++j) {
            v = v * DECAY_F + ca[j];
            float s = (v > 1.0f) ? 1.0f : 0.f;
            v *= (1.f - s);
            ca[j] = s;
        }
#pragma unroll
        for (int j = 0; j < UT; ++j) p[(size_t)(t0 + j) * N_OUT] = ca[j];
        if (t0 + UT >= T) break;
        if (t0 + 2 * UT < T) {
#pragma unroll
            for (int j = 0; j < UT; ++j) ca[j] = p[(size_t)(t0 + 2 * UT + j) * N_OUT];
        }
#pragma unroll
        for (int j = 0; j < UT; ++j) {
            v = v * DECAY_F + cb[j];
            float s = (v > 1.0f) ? 1.0f : 0.f;
            v *= (1.f - s);
            cb[j] = s;
        }
#pragma unroll
        for (int j = 0; j < UT; ++j) p[(size_t)(t0 + UT + j) * N_OUT] = cb[j];
    }
}

// ---------------- fallback: v3 gather path ----------------
__global__ __launch_bounds__(256) void transpose_w(const float* __restrict__ W,
                                                   float* __restrict__ WT) {
    __shared__ float t[32][33];
    const int k0 = blockIdx.x * 32;
    const int n0 = blockIdx.y * 32;
    const int lx = threadIdx.x & 31;
    const int ly = threadIdx.x >> 5;
#pragma unroll
    for (int r = ly; r < 32; r += 8)
        t[r][lx] = W[(size_t)(n0 + r) * N_IN + k0 + lx];
    __syncthreads();
#pragma unroll
    for (int r = ly; r < 32; r += 8)
        WT[(size_t)(k0 + r) * N_OUT + n0 + lx] = t[lx][r];
}

__global__ __launch_bounds__(256) void gather_rows(
        const float* __restrict__ S, const float* __restrict__ WT,
        float* __restrict__ I, int M) {
    const int wid  = blockIdx.x * 4 + (threadIdx.x >> 6);
    const int lane = threadIdx.x & 63;
    if (wid >= M) return;
    const float* srow = S + (size_t)wid * N_IN;
    float4 a0 = {0.f, 0.f, 0.f, 0.f};
    float4 a1 = {0.f, 0.f, 0.f, 0.f};
    float sv[16];
#pragma unroll
    for (int g = 0; g < 16; ++g) sv[g] = srow[g * 64 + lane];
#pragma unroll
    for (int g = 0; g < 16; ++g) {
        unsigned long long m = __ballot(sv[g] != 0.0f);
        while (m) {
            const int b = __builtin_ctzll(m);
            m &= m - 1;
            const int k = g * 64 + b;
            const float* wp = WT + (size_t)k * N_OUT + lane * 4;
            const float4 w0 = *reinterpret_cast<const float4*>(wp);
            const float4 w1 = *reinterpret_cast<const float4*>(wp + 256);
            a0.x += w0.x; a0.y += w0.y; a0.z += w0.z; a0.w += w0.w;
            a1.x += w1.x; a1.y += w1.y; a1.z += w1.z; a1.w += w1.w;
        }
    }
    float* op = I + (size_t)wid * N_OUT + lane * 4;
    *reinterpret_cast<float4*>(op) = a0;
    *reinterpret_cast<float4*>(op + 256) = a1;
}

extern "C" void kernel_launch(void* const* d_in, const int* in_sizes, int n_in,
                              void* d_out, int out_size, void* d_ws, size_t ws_size,
                              hipStream_t stream) {
    const float* S = (const float*)d_in[0];   // (B, T, n_in) binary spikes, fp32
    const float* W = (const float*)d_in[1];   // (n_out, n_in), fp32
    float* out = (float*)d_out;               // (B, T, n_out), fp32

    const int K = N_IN;
    const int M = in_sizes[0] / K;            // 32000
    const int B = 32;
    const int T = M / B;                      // 1000

    const size_t s8_bytes = (size_t)M * N_IN;                 // 32.77 MB
    const size_t d8_bytes = (size_t)4 * N_OUT * N_IN;         // 2 MB
    const size_t need = s8_bytes + d8_bytes;

    if (ws_size >= need && (M % BM) == 0) {
        signed char* S8 = (signed char*)d_ws;
        signed char* D8 = (signed char*)d_ws + s8_bytes;
        const int n16 = M * N_IN / 16;
        s_to_i8<<<(n16 + 255) / 256, 256, 0, stream>>>(S, S8, n16);
        w_digits<<<N_OUT, 256, 0, stream>>>(W, D8);
        const size_t lds_bytes = (size_t)4 * ABUF;            // 65536
        gemm_i8<<<(M / BM) * (N_OUT / BN), 512, lds_bytes, stream>>>(S8, D8, out, M);
        lif_scan3<<<(B * N_OUT) / 64, 64, 0, stream>>>(out, T);
    } else if (ws_size >= (size_t)N_IN * N_OUT * sizeof(float) && (M % 4) == 0) {
        float* WT = (float*)d_ws;
        dim3 tg(N_IN / 32, N_OUT / 32);
        transpose_w<<<tg, 256, 0, stream>>>(W, WT);
        gather_rows<<<M / 4, 256, 0, stream>>>(S, WT, out, M);
        lif_scan3<<<(B * N_OUT) / 64, 64, 0, stream>>>(out, T);
    }
}

// Round 8
// 193.366 us; speedup vs baseline: 6.8472x; 6.8472x over previous
//
#include <hip/hip_runtime.h>

// LIF spiking net forward, v7 — exact fixed-point i8 MFMA GEMM with fused
// fp32->i8 conversion in the staging path (s_to_i8 kernel eliminated).
//   W -> 4 signed base-256 digits of round(W * 2^34)  (exact, top digit <=85)
//   I = sum_d 2^(8d) * (S @ digit_d^T)  combined in int64, one fp32 round.
//   Quantization error <= 51 * 2^-35 ~ 1.5e-9  (no spike flips; absmax 0.0).
// v7: GEMM reverted to v5 structure (PITCH 80, launch_bounds(512,2) -- the
//     (512,4) cap in v6 spilled the 128-reg accumulator to scratch, 16x
//     regression). A is loaded as fp32 and packed to i8 in registers.

#define N_IN   1024
#define N_OUT  512
#define DECAY_F 0.95122942450071400910f
#define SCALE     17179869184.0            // 2^34
#define SCALE_INV 5.8207660913467407e-11f  // 2^-34

typedef int  v4i  __attribute__((ext_vector_type(4)));
typedef int  v16i __attribute__((ext_vector_type(16)));

__device__ __forceinline__ int pack4(float4 f) {
    const unsigned a = (f.x != 0.f) ? 1u : 0u;
    const unsigned b = (f.y != 0.f) ? 1u : 0u;
    const unsigned c = (f.z != 0.f) ? 1u : 0u;
    const unsigned d = (f.w != 0.f) ? 1u : 0u;
    return (int)(a | (b << 8) | (c << 16) | (d << 24));
}

// ---------------- kernel 2: W -> 4 digit planes ----------------
__global__ __launch_bounds__(256) void w_digits(const float* __restrict__ W,
                                                signed char* __restrict__ D8) {
    const int n  = blockIdx.x;            // 0..511
    const int k0 = threadIdx.x * 4;       // 0..1020
    const float4 wv = *reinterpret_cast<const float4*>(W + (size_t)n * N_IN + k0);
    const float ww[4] = {wv.x, wv.y, wv.z, wv.w};
    int pk[4] = {0, 0, 0, 0};
#pragma unroll
    for (int j = 0; j < 4; ++j) {
        long long wi = (long long)rint((double)ww[j] * SCALE);
        const int d0 = (int)((wi + 128) & 255) - 128; wi = (wi - d0) >> 8;
        const int d1 = (int)((wi + 128) & 255) - 128; wi = (wi - d1) >> 8;
        const int d2 = (int)((wi + 128) & 255) - 128; wi = (wi - d2) >> 8;
        const int d3 = (int)wi;           // |d3| <= 85
        pk[0] |= (d0 & 255) << (8 * j);
        pk[1] |= (d1 & 255) << (8 * j);
        pk[2] |= (d2 & 255) << (8 * j);
        pk[3] |= (d3 & 255) << (8 * j);
    }
#pragma unroll
    for (int d = 0; d < 4; ++d)
        *reinterpret_cast<int*>(D8 + (size_t)(d * N_OUT + n) * N_IN + k0) = pk[d];
}

// ---------------- kernel 3: i8 MFMA GEMM, fused A-conversion ----------------
#define BM 256
#define BN 64
#define BK 64
#define PITCH 80
#define ABUF (BM * PITCH)
#define ASH(buf) (lds + (buf) * ABUF)
#define BSH(buf) (lds + 2 * ABUF + (buf) * ABUF)

__global__ __launch_bounds__(512, 2) void gemm_i8(
        const float* __restrict__ S,          // (M, 1024) fp32 binary spikes
        const signed char* __restrict__ D8,   // (2048, 1024), row = d*512+n
        float* __restrict__ I, int M) {       // (M, 512)
    extern __shared__ signed char lds[];

    const int tid  = threadIdx.x;
    const int lane = tid & 63;
    const int w    = tid >> 6;
    const int wwm  = w >> 1;            // 0..3 -> M offset *64
    const int wwn  = w & 1;             // 0..1 -> N offset *32

    // XCD-aware swizzle: contiguous bm-range per XCD (A-tile L2 reuse).
    const int nx  = M / BM;                       // 125
    const int u   = (blockIdx.x & 7) * nx + (blockIdx.x >> 3);
    const int bm  = u >> 3;
    const int bn  = u & 7;
    const int m0 = bm * BM;
    const int n0 = bn * BN;

    const int srow = tid >> 2;           // 0..127
    const int scol = (tid & 3) * 16;     // element col 0..48 step 16

    v16i acc[2][4];
#pragma unroll
    for (int mf = 0; mf < 2; ++mf)
#pragma unroll
        for (int d = 0; d < 4; ++d)
#pragma unroll
            for (int i = 0; i < 16; ++i) acc[mf][d][i] = 0;

    // two named register staging sets (compile-time indexed; rule #20)
    float4 pf0, pf1, pf2, pf3, pf4, pf5, pf6, pf7;   // A fp32 (2 rows x 16)
    float4 qf0, qf1, qf2, qf3, qf4, qf5, qf6, qf7;
    int4 pb0, pb1, qb0, qb1;                          // B i8

#define LOADT(SET, kt)                                                            \
    {                                                                             \
        const float* ap0 = S + (size_t)(m0 + srow) * N_IN + (kt) * BK + scol;     \
        const float* ap1 = S + (size_t)(m0 + srow + 128) * N_IN + (kt) * BK + scol; \
        SET##f0 = *reinterpret_cast<const float4*>(ap0 + 0);                      \
        SET##f1 = *reinterpret_cast<const float4*>(ap0 + 4);                      \
        SET##f2 = *reinterpret_cast<const float4*>(ap0 + 8);                      \
        SET##f3 = *reinterpret_cast<const float4*>(ap0 + 12);                     \
        SET##f4 = *reinterpret_cast<const float4*>(ap1 + 0);                      \
        SET##f5 = *reinterpret_cast<const float4*>(ap1 + 4);                      \
        SET##f6 = *reinterpret_cast<const float4*>(ap1 + 8);                      \
        SET##f7 = *reinterpret_cast<const float4*>(ap1 + 12);                     \
        SET##b0 = *reinterpret_cast<const int4*>(D8 + (size_t)(((srow >> 6) * N_OUT) + n0 + (srow & 63)) * N_IN + (kt) * BK + scol);            \
        SET##b1 = *reinterpret_cast<const int4*>(D8 + (size_t)(((srow >> 6) * N_OUT + 2 * N_OUT) + n0 + (srow & 63)) * N_IN + (kt) * BK + scol); \
    }

#define WRITET(buf, SET)                                                          \
    {                                                                             \
        int4 wa0, wa1;                                                            \
        wa0.x = pack4(SET##f0); wa0.y = pack4(SET##f1);                           \
        wa0.z = pack4(SET##f2); wa0.w = pack4(SET##f3);                           \
        wa1.x = pack4(SET##f4); wa1.y = pack4(SET##f5);                           \
        wa1.z = pack4(SET##f6); wa1.w = pack4(SET##f7);                           \
        *reinterpret_cast<int4*>(ASH(buf) + (srow) * PITCH + scol) = wa0;         \
        *reinterpret_cast<int4*>(ASH(buf) + (srow + 128) * PITCH + scol) = wa1;   \
        *reinterpret_cast<int4*>(BSH(buf) + (srow) * PITCH + scol) = SET##b0;     \
        *reinterpret_cast<int4*>(BSH(buf) + (srow + 128) * PITCH + scol) = SET##b1; \
    }

    const int fr = lane & 31;                 // fragment row/col
    const int kh = (lane >> 5) * 16;          // k-half byte offset

#define COMPUTE(buf)                                                              \
    _Pragma("unroll")                                                             \
    for (int ksub = 0; ksub < 2; ++ksub) {                                        \
        const int kb = ksub * 32 + kh;                                            \
        v4i af0 = *reinterpret_cast<const v4i*>(ASH(buf) + (wwm * 64 + fr) * PITCH + kb);       \
        v4i af1 = *reinterpret_cast<const v4i*>(ASH(buf) + (wwm * 64 + 32 + fr) * PITCH + kb);  \
        v4i bf[4];                                                                \
        _Pragma("unroll")                                                         \
        for (int d = 0; d < 4; ++d)                                               \
            bf[d] = *reinterpret_cast<const v4i*>(BSH(buf) + (d * 64 + wwn * 32 + fr) * PITCH + kb); \
        __builtin_amdgcn_s_setprio(1);                                            \
        _Pragma("unroll")                                                         \
        for (int d = 0; d < 4; ++d) {                                             \
            acc[0][d] = __builtin_amdgcn_mfma_i32_32x32x32_i8(af0, bf[d], acc[0][d], 0, 0, 0); \
            acc[1][d] = __builtin_amdgcn_mfma_i32_32x32x32_i8(af1, bf[d], acc[1][d], 0, 0, 0); \
        }                                                                         \
        __builtin_amdgcn_s_setprio(0);                                            \
    }

    // prologue: tile0 -> LDS buf0; tile1 -> p; tile2 -> q (in flight)
    LOADT(p, 0);
    WRITET(0, p);
    LOADT(p, 1);
    LOADT(q, 2);
    __syncthreads();

#pragma unroll 1
    for (int kt = 0; kt < 16; kt += 2) {
        WRITET(1, p);
        if (kt + 3 <= 15) { LOADT(p, kt + 3); }
        COMPUTE(0);
        __syncthreads();
        if (kt + 2 <= 15) {
            WRITET(0, q);
            if (kt + 4 <= 15) { LOADT(q, kt + 4); }
        }
        COMPUTE(1);
        __syncthreads();
    }

    // epilogue: combine digits in int64, one fp32 rounding
    const int col = fr;
    const int rb_ = (lane >> 5) * 4;
#pragma unroll
    for (int mf = 0; mf < 2; ++mf) {
#pragma unroll
        for (int reg = 0; reg < 16; ++reg) {
            const int row = (reg & 3) + 8 * (reg >> 2) + rb_;
            const long long v =
                ((long long)acc[mf][3][reg] << 24) + ((long long)acc[mf][2][reg] << 16) +
                ((long long)acc[mf][1][reg] << 8) + (long long)acc[mf][0][reg];
            I[(size_t)(m0 + wwm * 64 + mf * 32 + row) * N_OUT + n0 + wwn * 32 + col] =
                (float)v * SCALE_INV;
        }
    }
}
#undef LOADT
#undef WRITET
#undef COMPUTE

// ---------------- kernel 4: LIF scan, phase-unrolled prefetch ----------------
#define UT 50
__global__ __launch_bounds__(64) void lif_scan3(float* __restrict__ IO, int T) {
    const int idx = blockIdx.x * 64 + threadIdx.x;   // chain id, 16384 total
    const int b = idx >> 9, o = idx & (N_OUT - 1);
    float* p = IO + (size_t)b * T * N_OUT + o;
    float ca[UT], cb[UT];
    float v = 0.f;
#pragma unroll
    for (int j = 0; j < UT; ++j) ca[j] = p[(size_t)j * N_OUT];
#pragma unroll 1
    for (int t0 = 0; t0 < T; t0 += 2 * UT) {
        if (t0 + UT < T) {
#pragma unroll
            for (int j = 0; j < UT; ++j) cb[j] = p[(size_t)(t0 + UT + j) * N_OUT];
        }
#pragma unroll
        for (int j = 0; j < UT; ++j) {
            v = v * DECAY_F + ca[j];
            float s = (v > 1.0f) ? 1.0f : 0.f;
            v *= (1.f - s);
            ca[j] = s;
        }
#pragma unroll
        for (int j = 0; j < UT; ++j) p[(size_t)(t0 + j) * N_OUT] = ca[j];
        if (t0 + UT >= T) break;
        if (t0 + 2 * UT < T) {
#pragma unroll
            for (int j = 0; j < UT; ++j) ca[j] = p[(size_t)(t0 + 2 * UT + j) * N_OUT];
        }
#pragma unroll
        for (int j = 0; j < UT; ++j) {
            v = v * DECAY_F + cb[j];
            float s = (v > 1.0f) ? 1.0f : 0.f;
            v *= (1.f - s);
            cb[j] = s;
        }
#pragma unroll
        for (int j = 0; j < UT; ++j) p[(size_t)(t0 + UT + j) * N_OUT] = cb[j];
    }
}

// ---------------- fallback: v3 gather path ----------------
__global__ __launch_bounds__(256) void transpose_w(const float* __restrict__ W,
                                                   float* __restrict__ WT) {
    __shared__ float t[32][33];
    const int k0 = blockIdx.x * 32;
    const int n0 = blockIdx.y * 32;
    const int lx = threadIdx.x & 31;
    const int ly = threadIdx.x >> 5;
#pragma unroll
    for (int r = ly; r < 32; r += 8)
        t[r][lx] = W[(size_t)(n0 + r) * N_IN + k0 + lx];
    __syncthreads();
#pragma unroll
    for (int r = ly; r < 32; r += 8)
        WT[(size_t)(k0 + r) * N_OUT + n0 + lx] = t[lx][r];
}

__global__ __launch_bounds__(256) void gather_rows(
        const float* __restrict__ S, const float* __restrict__ WT,
        float* __restrict__ I, int M) {
    const int wid  = blockIdx.x * 4 + (threadIdx.x >> 6);
    const int lane = threadIdx.x & 63;
    if (wid >= M) return;
    const float* srow = S + (size_t)wid * N_IN;
    float4 a0 = {0.f, 0.f, 0.f, 0.f};
    float4 a1 = {0.f, 0.f, 0.f, 0.f};
    float sv[16];
#pragma unroll
    for (int g = 0; g < 16; ++g) sv[g] = srow[g * 64 + lane];
#pragma unroll
    for (int g = 0; g < 16; ++g) {
        unsigned long long m = __ballot(sv[g] != 0.0f);
        while (m) {
            const int b = __builtin_ctzll(m);
            m &= m - 1;
            const int k = g * 64 + b;
            const float* wp = WT + (size_t)k * N_OUT + lane * 4;
            const float4 w0 = *reinterpret_cast<const float4*>(wp);
            const float4 w1 = *reinterpret_cast<const float4*>(wp + 256);
            a0.x += w0.x; a0.y += w0.y; a0.z += w0.z; a0.w += w0.w;
            a1.x += w1.x; a1.y += w1.y; a1.z += w1.z; a1.w += w1.w;
        }
    }
    float* op = I + (size_t)wid * N_OUT + lane * 4;
    *reinterpret_cast<float4*>(op) = a0;
    *reinterpret_cast<float4*>(op + 256) = a1;
}

extern "C" void kernel_launch(void* const* d_in, const int* in_sizes, int n_in,
                              void* d_out, int out_size, void* d_ws, size_t ws_size,
                              hipStream_t stream) {
    const float* S = (const float*)d_in[0];   // (B, T, n_in) binary spikes, fp32
    const float* W = (const float*)d_in[1];   // (n_out, n_in), fp32
    float* out = (float*)d_out;               // (B, T, n_out), fp32

    const int K = N_IN;
    const int M = in_sizes[0] / K;            // 32000
    const int B = 32;
    const int T = M / B;                      // 1000

    const size_t d8_bytes = (size_t)4 * N_OUT * N_IN;         // 2 MB

    if (ws_size >= d8_bytes && (M % BM) == 0) {
        signed char* D8 = (signed char*)d_ws;
        w_digits<<<N_OUT, 256, 0, stream>>>(W, D8);
        const size_t lds_bytes = (size_t)4 * ABUF;            // 81920
        gemm_i8<<<(M / BM) * (N_OUT / BN), 512, lds_bytes, stream>>>(S, D8, out, M);
        lif_scan3<<<(B * N_OUT) / 64, 64, 0, stream>>>(out, T);
    } else if (ws_size >= (size_t)N_IN * N_OUT * sizeof(float) && (M % 4) == 0) {
        float* WT = (float*)d_ws;
        dim3 tg(N_IN / 32, N_OUT / 32);
        transpose_w<<<tg, 256, 0, stream>>>(W, WT);
        gather_rows<<<M / 4, 256, 0, stream>>>(S, WT, out, M);
        lif_scan3<<<(B * N_OUT) / 64, 64, 0, stream>>>(out, T);
    }
}

// Round 9
// 147.463 us; speedup vs baseline: 8.9786x; 1.3113x over previous
//
#include <hip/hip_runtime.h>

// LIF spiking net forward, v8 — v5's proven GEMM + 256-CU LIF scan.
//   W -> 4 signed base-256 digits of round(W * 2^34)  (exact, top digit <=85)
//   S (binary fp32) -> i8
//   I = sum_d 2^(8d) * (S_i8 @ digit_d^T)  combined in int64, one fp32 round.
//   Quantization error <= 51 * 2^-35 ~ 1.5e-9  (no spike flips; absmax 0.0).
// v8: reverted v7's fused A-conversion (cost 114us in the GEMM to save a
//     26us HBM-floor kernel); scan uses 64-thread blocks so all 256 CUs
//     participate with 50 loads in flight per wave.

#define N_IN   1024
#define N_OUT  512
#define DECAY_F 0.95122942450071400910f
#define SCALE     17179869184.0            // 2^34
#define SCALE_INV 5.8207660913467407e-11f  // 2^-34

typedef int  v4i  __attribute__((ext_vector_type(4)));
typedef int  v16i __attribute__((ext_vector_type(16)));

// ---------------- kernel 1: S fp32 -> i8 ----------------
__global__ __launch_bounds__(256) void s_to_i8(const float* __restrict__ S,
                                               signed char* __restrict__ S8,
                                               int n16) {
    const int g = blockIdx.x * 256 + threadIdx.x;
    if (g >= n16) return;
    const float4* p = reinterpret_cast<const float4*>(S) + (size_t)g * 4;
    union { signed char c[16]; int4 v; } u;
#pragma unroll
    for (int q = 0; q < 4; ++q) {
        const float4 v = p[q];
        u.c[q * 4 + 0] = (signed char)(v.x != 0.f);
        u.c[q * 4 + 1] = (signed char)(v.y != 0.f);
        u.c[q * 4 + 2] = (signed char)(v.z != 0.f);
        u.c[q * 4 + 3] = (signed char)(v.w != 0.f);
    }
    reinterpret_cast<int4*>(S8)[g] = u.v;
}

// ---------------- kernel 2: W -> 4 digit planes ----------------
__global__ __launch_bounds__(256) void w_digits(const float* __restrict__ W,
                                                signed char* __restrict__ D8) {
    const int n  = blockIdx.x;            // 0..511
    const int k0 = threadIdx.x * 4;       // 0..1020
    const float4 wv = *reinterpret_cast<const float4*>(W + (size_t)n * N_IN + k0);
    const float ww[4] = {wv.x, wv.y, wv.z, wv.w};
    int pk[4] = {0, 0, 0, 0};
#pragma unroll
    for (int j = 0; j < 4; ++j) {
        long long wi = (long long)rint((double)ww[j] * SCALE);
        const int d0 = (int)((wi + 128) & 255) - 128; wi = (wi - d0) >> 8;
        const int d1 = (int)((wi + 128) & 255) - 128; wi = (wi - d1) >> 8;
        const int d2 = (int)((wi + 128) & 255) - 128; wi = (wi - d2) >> 8;
        const int d3 = (int)wi;           // |d3| <= 85
        pk[0] |= (d0 & 255) << (8 * j);
        pk[1] |= (d1 & 255) << (8 * j);
        pk[2] |= (d2 & 255) << (8 * j);
        pk[3] |= (d3 & 255) << (8 * j);
    }
#pragma unroll
    for (int d = 0; d < 4; ++d)
        *reinterpret_cast<int*>(D8 + (size_t)(d * N_OUT + n) * N_IN + k0) = pk[d];
}

// ---------------- kernel 3: i8 MFMA GEMM, depth-2 pipeline (v5) ----------------
#define BM 256
#define BN 64
#define BK 64
#define PITCH 80
#define ABUF (BM * PITCH)
#define ASH(buf) (lds + (buf) * ABUF)
#define BSH(buf) (lds + 2 * ABUF + (buf) * ABUF)

__global__ __launch_bounds__(512, 2) void gemm_i8(
        const signed char* __restrict__ S8,   // (M, 1024)
        const signed char* __restrict__ D8,   // (2048, 1024), row = d*512+n
        float* __restrict__ I, int M) {       // (M, 512)
    extern __shared__ signed char lds[];

    const int tid  = threadIdx.x;
    const int lane = tid & 63;
    const int w    = tid >> 6;
    const int wwm  = w >> 1;            // 0..3 -> M offset *64
    const int wwn  = w & 1;             // 0..1 -> N offset *32

    // XCD-aware swizzle: contiguous bm-range per XCD (A-tile L2 reuse).
    const int nx  = M / BM;                       // 125
    const int u   = (blockIdx.x & 7) * nx + (blockIdx.x >> 3);
    const int bm  = u >> 3;
    const int bn  = u & 7;
    const int m0 = bm * BM;
    const int n0 = bn * BN;

    const int srow = tid >> 2;           // 0..127
    const int scol = (tid & 3) * 16;     // 0..48

    v16i acc[2][4];
#pragma unroll
    for (int mf = 0; mf < 2; ++mf)
#pragma unroll
        for (int d = 0; d < 4; ++d)
#pragma unroll
            for (int i = 0; i < 16; ++i) acc[mf][d][i] = 0;

    // two named register staging sets (compile-time indexed; rule #20)
    int4 pa0, pa1, pb0, pb1;
    int4 qa0, qa1, qb0, qb1;

#define LOADT(SET, kt)                                                            \
    SET##a0 = *reinterpret_cast<const int4*>(S8 + (size_t)(m0 + srow) * N_IN + (kt) * BK + scol);        \
    SET##a1 = *reinterpret_cast<const int4*>(S8 + (size_t)(m0 + srow + 128) * N_IN + (kt) * BK + scol);  \
    SET##b0 = *reinterpret_cast<const int4*>(D8 + (size_t)(((srow >> 6) * N_OUT) + n0 + (srow & 63)) * N_IN + (kt) * BK + scol);            \
    SET##b1 = *reinterpret_cast<const int4*>(D8 + (size_t)(((srow >> 6) * N_OUT + 2 * N_OUT) + n0 + (srow & 63)) * N_IN + (kt) * BK + scol);

#define WRITET(buf, SET)                                                          \
    *reinterpret_cast<int4*>(ASH(buf) + (srow) * PITCH + scol) = SET##a0;         \
    *reinterpret_cast<int4*>(ASH(buf) + (srow + 128) * PITCH + scol) = SET##a1;   \
    *reinterpret_cast<int4*>(BSH(buf) + (srow) * PITCH + scol) = SET##b0;         \
    *reinterpret_cast<int4*>(BSH(buf) + (srow + 128) * PITCH + scol) = SET##b1;

    const int fr = lane & 31;                 // fragment row/col
    const int kh = (lane >> 5) * 16;          // k-half byte offset

#define COMPUTE(buf)                                                              \
    _Pragma("unroll")                                                             \
    for (int ksub = 0; ksub < 2; ++ksub) {                                        \
        const int kb = ksub * 32 + kh;                                            \
        v4i af0 = *reinterpret_cast<const v4i*>(ASH(buf) + (wwm * 64 + fr) * PITCH + kb);       \
        v4i af1 = *reinterpret_cast<const v4i*>(ASH(buf) + (wwm * 64 + 32 + fr) * PITCH + kb);  \
        v4i bf[4];                                                                \
        _Pragma("unroll")                                                         \
        for (int d = 0; d < 4; ++d)                                               \
            bf[d] = *reinterpret_cast<const v4i*>(BSH(buf) + (d * 64 + wwn * 32 + fr) * PITCH + kb); \
        __builtin_amdgcn_s_setprio(1);                                            \
        _Pragma("unroll")                                                         \
        for (int d = 0; d < 4; ++d) {                                             \
            acc[0][d] = __builtin_amdgcn_mfma_i32_32x32x32_i8(af0, bf[d], acc[0][d], 0, 0, 0); \
            acc[1][d] = __builtin_amdgcn_mfma_i32_32x32x32_i8(af1, bf[d], acc[1][d], 0, 0, 0); \
        }                                                                         \
        __builtin_amdgcn_s_setprio(0);                                            \
    }

    // prologue: tile0 -> LDS buf0; tile1 -> p; tile2 -> q (in flight)
    LOADT(p, 0);
    WRITET(0, p);
    LOADT(p, 1);
    LOADT(q, 2);
    __syncthreads();

#pragma unroll 1
    for (int kt = 0; kt < 16; kt += 2) {
        WRITET(1, p);
        if (kt + 3 <= 15) { LOADT(p, kt + 3); }
        COMPUTE(0);
        __syncthreads();
        if (kt + 2 <= 15) {
            WRITET(0, q);
            if (kt + 4 <= 15) { LOADT(q, kt + 4); }
        }
        COMPUTE(1);
        __syncthreads();
    }

    // epilogue: combine digits in int64, one fp32 rounding
    const int col = fr;
    const int rb_ = (lane >> 5) * 4;
#pragma unroll
    for (int mf = 0; mf < 2; ++mf) {
#pragma unroll
        for (int reg = 0; reg < 16; ++reg) {
            const int row = (reg & 3) + 8 * (reg >> 2) + rb_;
            const long long v =
                ((long long)acc[mf][3][reg] << 24) + ((long long)acc[mf][2][reg] << 16) +
                ((long long)acc[mf][1][reg] << 8) + (long long)acc[mf][0][reg];
            I[(size_t)(m0 + wwm * 64 + mf * 32 + row) * N_OUT + n0 + wwn * 32 + col] =
                (float)v * SCALE_INV;
        }
    }
}
#undef LOADT
#undef WRITET
#undef COMPUTE

// ---------------- kernel 4: LIF scan, 1 wave/CU, deep prefetch ----------------
#define UT 50
__global__ __launch_bounds__(64) void lif_scan3(float* __restrict__ IO, int T) {
    const int idx = blockIdx.x * 64 + threadIdx.x;   // chain id, 16384 total
    const int b = idx >> 9, o = idx & (N_OUT - 1);
    float* p = IO + (size_t)b * T * N_OUT + o;
    float ca[UT], cb[UT];
    float v = 0.f;
#pragma unroll
    for (int j = 0; j < UT; ++j) ca[j] = p[(size_t)j * N_OUT];
#pragma unroll 1
    for (int t0 = 0; t0 < T; t0 += 2 * UT) {
        if (t0 + UT < T) {
#pragma unroll
            for (int j = 0; j < UT; ++j) cb[j] = p[(size_t)(t0 + UT + j) * N_OUT];
        }
#pragma unroll
        for (int j = 0; j < UT; ++j) {
            v = v * DECAY_F + ca[j];
            float s = (v > 1.0f) ? 1.0f : 0.f;
            v *= (1.f - s);
            ca[j] = s;
        }
#pragma unroll
        for (int j = 0; j < UT; ++j) p[(size_t)(t0 + j) * N_OUT] = ca[j];
        if (t0 + UT >= T) break;
        if (t0 + 2 * UT < T) {
#pragma unroll
            for (int j = 0; j < UT; ++j) ca[j] = p[(size_t)(t0 + 2 * UT + j) * N_OUT];
        }
#pragma unroll
        for (int j = 0; j < UT; ++j) {
            v = v * DECAY_F + cb[j];
            float s = (v > 1.0f) ? 1.0f : 0.f;
            v *= (1.f - s);
            cb[j] = s;
        }
#pragma unroll
        for (int j = 0; j < UT; ++j) p[(size_t)(t0 + UT + j) * N_OUT] = cb[j];
    }
}

// ---------------- fallback: v3 gather path ----------------
__global__ __launch_bounds__(256) void transpose_w(const float* __restrict__ W,
                                                   float* __restrict__ WT) {
    __shared__ float t[32][33];
    const int k0 = blockIdx.x * 32;
    const int n0 = blockIdx.y * 32;
    const int lx = threadIdx.x & 31;
    const int ly = threadIdx.x >> 5;
#pragma unroll
    for (int r = ly; r < 32; r += 8)
        t[r][lx] = W[(size_t)(n0 + r) * N_IN + k0 + lx];
    __syncthreads();
#pragma unroll
    for (int r = ly; r < 32; r += 8)
        WT[(size_t)(k0 + r) * N_OUT + n0 + lx] = t[lx][r];
}

__global__ __launch_bounds__(256) void gather_rows(
        const float* __restrict__ S, const float* __restrict__ WT,
        float* __restrict__ I, int M) {
    const int wid  = blockIdx.x * 4 + (threadIdx.x >> 6);
    const int lane = threadIdx.x & 63;
    if (wid >= M) return;
    const float* srow = S + (size_t)wid * N_IN;
    float4 a0 = {0.f, 0.f, 0.f, 0.f};
    float4 a1 = {0.f, 0.f, 0.f, 0.f};
    float sv[16];
#pragma unroll
    for (int g = 0; g < 16; ++g) sv[g] = srow[g * 64 + lane];
#pragma unroll
    for (int g = 0; g < 16; ++g) {
        unsigned long long m = __ballot(sv[g] != 0.0f);
        while (m) {
            const int b = __builtin_ctzll(m);
            m &= m - 1;
            const int k = g * 64 + b;
            const float* wp = WT + (size_t)k * N_OUT + lane * 4;
            const float4 w0 = *reinterpret_cast<const float4*>(wp);
            const float4 w1 = *reinterpret_cast<const float4*>(wp + 256);
            a0.x += w0.x; a0.y += w0.y; a0.z += w0.z; a0.w += w0.w;
            a1.x += w1.x; a1.y += w1.y; a1.z += w1.z; a1.w += w1.w;
        }
    }
    float* op = I + (size_t)wid * N_OUT + lane * 4;
    *reinterpret_cast<float4*>(op) = a0;
    *reinterpret_cast<float4*>(op + 256) = a1;
}

extern "C" void kernel_launch(void* const* d_in, const int* in_sizes, int n_in,
                              void* d_out, int out_size, void* d_ws, size_t ws_size,
                              hipStream_t stream) {
    const float* S = (const float*)d_in[0];   // (B, T, n_in) binary spikes, fp32
    const float* W = (const float*)d_in[1];   // (n_out, n_in), fp32
    float* out = (float*)d_out;               // (B, T, n_out), fp32

    const int K = N_IN;
    const int M = in_sizes[0] / K;            // 32000
    const int B = 32;
    const int T = M / B;                      // 1000

    const size_t s8_bytes = (size_t)M * N_IN;                 // 32.77 MB
    const size_t d8_bytes = (size_t)4 * N_OUT * N_IN;         // 2 MB
    const size_t need = s8_bytes + d8_bytes;

    if (ws_size >= need && (M % BM) == 0) {
        signed char* S8 = (signed char*)d_ws;
        signed char* D8 = (signed char*)d_ws + s8_bytes;
        const int n16 = M * N_IN / 16;
        s_to_i8<<<(n16 + 255) / 256, 256, 0, stream>>>(S, S8, n16);
        w_digits<<<N_OUT, 256, 0, stream>>>(W, D8);
        const size_t lds_bytes = (size_t)4 * ABUF;            // 81920
        gemm_i8<<<(M / BM) * (N_OUT / BN), 512, lds_bytes, stream>>>(S8, D8, out, M);
        lif_scan3<<<(B * N_OUT) / 64, 64, 0, stream>>>(out, T);
    } else if (ws_size >= (size_t)N_IN * N_OUT * sizeof(float) && (M % 4) == 0) {
        float* WT = (float*)d_ws;
        dim3 tg(N_IN / 32, N_OUT / 32);
        transpose_w<<<tg, 256, 0, stream>>>(W, WT);
        gather_rows<<<M / 4, 256, 0, stream>>>(S, WT, out, M);
        lif_scan3<<<(B * N_OUT) / 64, 64, 0, stream>>>(out, T);
    }
}

// Round 10
// 147.270 us; speedup vs baseline: 8.9904x; 1.0013x over previous
//
#include <hip/hip_runtime.h>

// LIF spiking net forward, v9 — exact fixed-point i8 MFMA GEMM, BM=128 for
// 2 blocks/CU co-residency (cross-block phase overlap), deeper LIF scan.
//   W -> 4 signed base-256 digits of round(W * 2^34)  (exact, top digit <=85)
//   S (binary fp32) -> i8
//   I = sum_d 2^(8d) * (S_i8 @ digit_d^T)  combined in int64, one fp32 round.
//   Quantization error <= 51 * 2^-35 ~ 1.5e-9  (no spike flips; absmax 0.0).
// v9: 256-thread blocks (4 waves), LDS 60KB -> 2 blocks/CU WITHOUT register
//     caps (v6's (512,4) spilled acc); depth-1 reg staging; scan UT=100.

#define N_IN   1024
#define N_OUT  512
#define DECAY_F 0.95122942450071400910f
#define SCALE     17179869184.0            // 2^34
#define SCALE_INV 5.8207660913467407e-11f  // 2^-34

typedef int  v4i  __attribute__((ext_vector_type(4)));
typedef int  v16i __attribute__((ext_vector_type(16)));

// ---------------- kernel 1: S fp32 -> i8 ----------------
__global__ __launch_bounds__(256) void s_to_i8(const float* __restrict__ S,
                                               signed char* __restrict__ S8,
                                               int n16) {
    const int g = blockIdx.x * 256 + threadIdx.x;
    if (g >= n16) return;
    const float4* p = reinterpret_cast<const float4*>(S) + (size_t)g * 4;
    union { signed char c[16]; int4 v; } u;
#pragma unroll
    for (int q = 0; q < 4; ++q) {
        const float4 v = p[q];
        u.c[q * 4 + 0] = (signed char)(v.x != 0.f);
        u.c[q * 4 + 1] = (signed char)(v.y != 0.f);
        u.c[q * 4 + 2] = (signed char)(v.z != 0.f);
        u.c[q * 4 + 3] = (signed char)(v.w != 0.f);
    }
    reinterpret_cast<int4*>(S8)[g] = u.v;
}

// ---------------- kernel 2: W -> 4 digit planes ----------------
__global__ __launch_bounds__(256) void w_digits(const float* __restrict__ W,
                                                signed char* __restrict__ D8) {
    const int n  = blockIdx.x;            // 0..511
    const int k0 = threadIdx.x * 4;       // 0..1020
    const float4 wv = *reinterpret_cast<const float4*>(W + (size_t)n * N_IN + k0);
    const float ww[4] = {wv.x, wv.y, wv.z, wv.w};
    int pk[4] = {0, 0, 0, 0};
#pragma unroll
    for (int j = 0; j < 4; ++j) {
        long long wi = (long long)rint((double)ww[j] * SCALE);
        const int d0 = (int)((wi + 128) & 255) - 128; wi = (wi - d0) >> 8;
        const int d1 = (int)((wi + 128) & 255) - 128; wi = (wi - d1) >> 8;
        const int d2 = (int)((wi + 128) & 255) - 128; wi = (wi - d2) >> 8;
        const int d3 = (int)wi;           // |d3| <= 85
        pk[0] |= (d0 & 255) << (8 * j);
        pk[1] |= (d1 & 255) << (8 * j);
        pk[2] |= (d2 & 255) << (8 * j);
        pk[3] |= (d3 & 255) << (8 * j);
    }
#pragma unroll
    for (int d = 0; d < 4; ++d)
        *reinterpret_cast<int*>(D8 + (size_t)(d * N_OUT + n) * N_IN + k0) = pk[d];
}

// ---------------- kernel 3: i8 MFMA GEMM, BM=128, 2 blocks/CU ----------------
#define BM 128
#define BN 64
#define BK 64
#define PITCH 80
#define A_ROWS 128
#define B_ROWS 256
#define BUFSZ ((A_ROWS + B_ROWS) * PITCH)       // 30720
#define ASH(buf) (lds + (buf) * BUFSZ)
#define BSH(buf) (lds + (buf) * BUFSZ + A_ROWS * PITCH)

__global__ __launch_bounds__(256, 2) void gemm_i8(
        const signed char* __restrict__ S8,   // (M, 1024)
        const signed char* __restrict__ D8,   // (2048, 1024), row = d*512+n
        float* __restrict__ I, int M) {       // (M, 512)
    extern __shared__ signed char lds[];

    const int tid  = threadIdx.x;
    const int lane = tid & 63;
    const int w    = tid >> 6;          // 0..3
    const int wwm  = w >> 1;            // 0..1 -> M offset *64
    const int wwn  = w & 1;             // 0..1 -> N offset *32

    // XCD-aware bijective swizzle: grid = 2000 = 8*250.
    const int nx  = (M / BM) * (N_OUT / BN) / 8;  // 250
    const int u   = (blockIdx.x & 7) * nx + (blockIdx.x >> 3);
    const int bm  = u >> 3;
    const int bn  = u & 7;
    const int m0 = bm * BM;
    const int n0 = bn * BN;

    const int srow = tid >> 2;           // 0..63
    const int scol = (tid & 3) * 16;     // 0..48

    v16i acc[2][4];
#pragma unroll
    for (int mf = 0; mf < 2; ++mf)
#pragma unroll
        for (int d = 0; d < 4; ++d)
#pragma unroll
            for (int i = 0; i < 16; ++i) acc[mf][d][i] = 0;

    // depth-1 staging: one named set of 6 vectors (2 A rows + 4 B rows)
    int4 pa0, pa1, pb0, pb1, pb2, pb3;

#define LOADT(kt)                                                                 \
    pa0 = *reinterpret_cast<const int4*>(S8 + (size_t)(m0 + srow) * N_IN + (kt) * BK + scol);       \
    pa1 = *reinterpret_cast<const int4*>(S8 + (size_t)(m0 + srow + 64) * N_IN + (kt) * BK + scol);  \
    pb0 = *reinterpret_cast<const int4*>(D8 + (size_t)(0 * N_OUT + n0 + srow) * N_IN + (kt) * BK + scol); \
    pb1 = *reinterpret_cast<const int4*>(D8 + (size_t)(1 * N_OUT + n0 + srow) * N_IN + (kt) * BK + scol); \
    pb2 = *reinterpret_cast<const int4*>(D8 + (size_t)(2 * N_OUT + n0 + srow) * N_IN + (kt) * BK + scol); \
    pb3 = *reinterpret_cast<const int4*>(D8 + (size_t)(3 * N_OUT + n0 + srow) * N_IN + (kt) * BK + scol);

#define WRITET(buf)                                                               \
    *reinterpret_cast<int4*>(ASH(buf) + (srow) * PITCH + scol) = pa0;             \
    *reinterpret_cast<int4*>(ASH(buf) + (srow + 64) * PITCH + scol) = pa1;        \
    *reinterpret_cast<int4*>(BSH(buf) + (srow) * PITCH + scol) = pb0;             \
    *reinterpret_cast<int4*>(BSH(buf) + (srow + 64) * PITCH + scol) = pb1;        \
    *reinterpret_cast<int4*>(BSH(buf) + (srow + 128) * PITCH + scol) = pb2;       \
    *reinterpret_cast<int4*>(BSH(buf) + (srow + 192) * PITCH + scol) = pb3;

    const int fr = lane & 31;                 // fragment row/col
    const int kh = (lane >> 5) * 16;          // k-half byte offset

#define COMPUTE(buf)                                                              \
    _Pragma("unroll")                                                             \
    for (int ksub = 0; ksub < 2; ++ksub) {                                        \
        const int kb = ksub * 32 + kh;                                            \
        v4i af0 = *reinterpret_cast<const v4i*>(ASH(buf) + (wwm * 64 + fr) * PITCH + kb);       \
        v4i af1 = *reinterpret_cast<const v4i*>(ASH(buf) + (wwm * 64 + 32 + fr) * PITCH + kb);  \
        v4i bf[4];                                                                \
        _Pragma("unroll")                                                         \
        for (int d = 0; d < 4; ++d)                                               \
            bf[d] = *reinterpret_cast<const v4i*>(BSH(buf) + (d * 64 + wwn * 32 + fr) * PITCH + kb); \
        __builtin_amdgcn_s_setprio(1);                                            \
        _Pragma("unroll")                                                         \
        for (int d = 0; d < 4; ++d) {                                             \
            acc[0][d] = __builtin_amdgcn_mfma_i32_32x32x32_i8(af0, bf[d], acc[0][d], 0, 0, 0); \
            acc[1][d] = __builtin_amdgcn_mfma_i32_32x32x32_i8(af1, bf[d], acc[1][d], 0, 0, 0); \
        }                                                                         \
        __builtin_amdgcn_s_setprio(0);                                            \
    }

    // prologue
    LOADT(0);
    WRITET(0);
    LOADT(1);
    __syncthreads();

#pragma unroll 1
    for (int kt = 0; kt < 16; kt += 2) {
        // even: compute buf0 (tile kt); stage tile kt+1 into buf1
        WRITET(1);
        if (kt + 2 <= 15) { LOADT(kt + 2); }
        COMPUTE(0);
        __syncthreads();
        // odd: compute buf1 (tile kt+1); stage tile kt+2 into buf0
        if (kt + 2 <= 15) {
            WRITET(0);
            if (kt + 3 <= 15) { LOADT(kt + 3); }
        }
        COMPUTE(1);
        __syncthreads();
    }

    // epilogue: combine digits in int64, one fp32 rounding
    const int col = fr;
    const int rb_ = (lane >> 5) * 4;
#pragma unroll
    for (int mf = 0; mf < 2; ++mf) {
#pragma unroll
        for (int reg = 0; reg < 16; ++reg) {
            const int row = (reg & 3) + 8 * (reg >> 2) + rb_;
            const long long v =
                ((long long)acc[mf][3][reg] << 24) + ((long long)acc[mf][2][reg] << 16) +
                ((long long)acc[mf][1][reg] << 8) + (long long)acc[mf][0][reg];
            I[(size_t)(m0 + wwm * 64 + mf * 32 + row) * N_OUT + n0 + wwn * 32 + col] =
                (float)v * SCALE_INV;
        }
    }
}
#undef LOADT
#undef WRITET
#undef COMPUTE

// ---------------- kernel 4: LIF scan, deep prefetch ----------------
#define UT 100
__global__ __launch_bounds__(64, 1) void lif_scan3(float* __restrict__ IO, int T) {
    const int idx = blockIdx.x * 64 + threadIdx.x;   // chain id, 16384 total
    const int b = idx >> 9, o = idx & (N_OUT - 1);
    float* p = IO + (size_t)b * T * N_OUT + o;
    float ca[UT], cb[UT];
    float v = 0.f;
#pragma unroll
    for (int j = 0; j < UT; ++j) ca[j] = p[(size_t)j * N_OUT];
#pragma unroll 1
    for (int t0 = 0; t0 < T; t0 += 2 * UT) {
        if (t0 + UT < T) {
#pragma unroll
            for (int j = 0; j < UT; ++j) cb[j] = p[(size_t)(t0 + UT + j) * N_OUT];
        }
#pragma unroll
        for (int j = 0; j < UT; ++j) {
            v = v * DECAY_F + ca[j];
            float s = (v > 1.0f) ? 1.0f : 0.f;
            v *= (1.f - s);
            ca[j] = s;
        }
#pragma unroll
        for (int j = 0; j < UT; ++j) p[(size_t)(t0 + j) * N_OUT] = ca[j];
        if (t0 + UT >= T) break;
        if (t0 + 2 * UT < T) {
#pragma unroll
            for (int j = 0; j < UT; ++j) ca[j] = p[(size_t)(t0 + 2 * UT + j) * N_OUT];
        }
#pragma unroll
        for (int j = 0; j < UT; ++j) {
            v = v * DECAY_F + cb[j];
            float s = (v > 1.0f) ? 1.0f : 0.f;
            v *= (1.f - s);
            cb[j] = s;
        }
#pragma unroll
        for (int j = 0; j < UT; ++j) p[(size_t)(t0 + UT + j) * N_OUT] = cb[j];
    }
}

// ---------------- fallback: v3 gather path ----------------
__global__ __launch_bounds__(256) void transpose_w(const float* __restrict__ W,
                                                   float* __restrict__ WT) {
    __shared__ float t[32][33];
    const int k0 = blockIdx.x * 32;
    const int n0 = blockIdx.y * 32;
    const int lx = threadIdx.x & 31;
    const int ly = threadIdx.x >> 5;
#pragma unroll
    for (int r = ly; r < 32; r += 8)
        t[r][lx] = W[(size_t)(n0 + r) * N_IN + k0 + lx];
    __syncthreads();
#pragma unroll
    for (int r = ly; r < 32; r += 8)
        WT[(size_t)(k0 + r) * N_OUT + n0 + lx] = t[lx][r];
}

__global__ __launch_bounds__(256) void gather_rows(
        const float* __restrict__ S, const float* __restrict__ WT,
        float* __restrict__ I, int M) {
    const int wid  = blockIdx.x * 4 + (threadIdx.x >> 6);
    const int lane = threadIdx.x & 63;
    if (wid >= M) return;
    const float* srow = S + (size_t)wid * N_IN;
    float4 a0 = {0.f, 0.f, 0.f, 0.f};
    float4 a1 = {0.f, 0.f, 0.f, 0.f};
    float sv[16];
#pragma unroll
    for (int g = 0; g < 16; ++g) sv[g] = srow[g * 64 + lane];
#pragma unroll
    for (int g = 0; g < 16; ++g) {
        unsigned long long m = __ballot(sv[g] != 0.0f);
        while (m) {
            const int b = __builtin_ctzll(m);
            m &= m - 1;
            const int k = g * 64 + b;
            const float* wp = WT + (size_t)k * N_OUT + lane * 4;
            const float4 w0 = *reinterpret_cast<const float4*>(wp);
            const float4 w1 = *reinterpret_cast<const float4*>(wp + 256);
            a0.x += w0.x; a0.y += w0.y; a0.z += w0.z; a0.w += w0.w;
            a1.x += w1.x; a1.y += w1.y; a1.z += w1.z; a1.w += w1.w;
        }
    }
    float* op = I + (size_t)wid * N_OUT + lane * 4;
    *reinterpret_cast<float4*>(op) = a0;
    *reinterpret_cast<float4*>(op + 256) = a1;
}

extern "C" void kernel_launch(void* const* d_in, const int* in_sizes, int n_in,
                              void* d_out, int out_size, void* d_ws, size_t ws_size,
                              hipStream_t stream) {
    const float* S = (const float*)d_in[0];   // (B, T, n_in) binary spikes, fp32
    const float* W = (const float*)d_in[1];   // (n_out, n_in), fp32
    float* out = (float*)d_out;               // (B, T, n_out), fp32

    const int K = N_IN;
    const int M = in_sizes[0] / K;            // 32000
    const int B = 32;
    const int T = M / B;                      // 1000

    const size_t s8_bytes = (size_t)M * N_IN;                 // 32.77 MB
    const size_t d8_bytes = (size_t)4 * N_OUT * N_IN;         // 2 MB
    const size_t need = s8_bytes + d8_bytes;

    if (ws_size >= need && (M % BM) == 0 && ((M / BM) * (N_OUT / BN)) % 8 == 0) {
        signed char* S8 = (signed char*)d_ws;
        signed char* D8 = (signed char*)d_ws + s8_bytes;
        const int n16 = M * N_IN / 16;
        s_to_i8<<<(n16 + 255) / 256, 256, 0, stream>>>(S, S8, n16);
        w_digits<<<N_OUT, 256, 0, stream>>>(W, D8);
        const size_t lds_bytes = (size_t)2 * BUFSZ;           // 61440
        gemm_i8<<<(M / BM) * (N_OUT / BN), 256, lds_bytes, stream>>>(S8, D8, out, M);
        lif_scan3<<<(B * N_OUT) / 64, 64, 0, stream>>>(out, T);
    } else if (ws_size >= (size_t)N_IN * N_OUT * sizeof(float) && (M % 4) == 0) {
        float* WT = (float*)d_ws;
        dim3 tg(N_IN / 32, N_OUT / 32);
        transpose_w<<<tg, 256, 0, stream>>>(W, WT);
        gather_rows<<<M / 4, 256, 0, stream>>>(S, WT, out, M);
        lif_scan3<<<(B * N_OUT) / 64, 64, 0, stream>>>(out, T);
    }
}